// Round 12
// baseline (274.157 us; speedup 1.0000x reference)
//
#include <hip/hip_runtime.h>
#include <stdint.h>

// B=8, S=1024, D_MODEL=256, dk=dv=16, 128 pseudo-heads of 1024x16.
// ws layout (floats): Q[2M] | K[2M] | V(f16, 1M floats) | AO[2M] | Wplanes[256K]
// Wplanes: 4 matrices x { hi[256][256], lo[256][256] } f16, layout [n][k].

typedef _Float16 f16x8 __attribute__((ext_vector_type(8)));
typedef _Float16 f16x4 __attribute__((ext_vector_type(4)));
typedef float    f32x4 __attribute__((ext_vector_type(4)));

// ---------------------------------------------------------------------------
// prepW: one-shot transpose + split-f16 conversion of the four weight
// matrices (f32 [k][n] -> f16 hi/lo planes [n][k]). Coalesced via LDS tiles.
// ---------------------------------------------------------------------------
__global__ __launch_bounds__(256) void prepW(
    const float* __restrict__ Wq, const float* __restrict__ Wk,
    const float* __restrict__ Wv, const float* __restrict__ Wo,
    _Float16* __restrict__ P)
{
    __shared__ float T[64][65];
    const int mat = blockIdx.y;
    const float* W = (mat == 0) ? Wq : (mat == 1) ? Wk : (mat == 2) ? Wv : Wo;
    const int tk = blockIdx.x >> 2, tn = blockIdx.x & 3;   // 4x4 tiles of 64
    const int t  = threadIdx.x;
    const int cl = t & 63, rg = t >> 6;

    #pragma unroll
    for (int r = 0; r < 16; ++r) {
        const int k = (rg << 4) + r;                       // local k
        T[k][cl] = W[(size_t)((tk << 6) + k) * 256 + (tn << 6) + cl];
    }
    __syncthreads();
    _Float16* hi = P + ((size_t)mat << 17);                // 2*65536 f16 per mat
    _Float16* lo = hi + 65536;
    #pragma unroll
    for (int r = 0; r < 16; ++r) {
        const int n = (rg << 4) + r;                       // local n
        const float v = T[cl][n];                          // transposed read
        const _Float16 h = (_Float16)v;
        const size_t o = (size_t)((tn << 6) + n) * 256 + (tk << 6) + cl;
        hi[o] = h;
        lo[o] = (_Float16)(v - (float)h);
    }
}

// ---------------------------------------------------------------------------
// Split-f16 MFMA GEMM: C[8192x256] = A @ W + bias.
// R23: 256-thread blocks, m-tile 128 via TWO 64-row groups per wave
// (acc[2][4]). Each Bh/Bl LDS read feeds 6 MFMAs (2 independent chains) ->
// 2x ILP, 2x MFMA per barrier-interval, half the W-staging per output row.
// LDS 34.8 KB, waves_per_eu(4,4) -> 4 blocks/CU, VGPR budget 128 (no spill
// risk; est ~95). MFMA order per acc unchanged -> bit-identical results.
// ---------------------------------------------------------------------------
__device__ __forceinline__ void gemm_mfma(const float* __restrict__ A,
                                          const _Float16* __restrict__ Whi,
                                          const _Float16* __restrict__ Wlo,
                                          const float* __restrict__ bias,
                                          float* __restrict__ C, int vf16)
{
    __shared__ _Float16 Bhi[64][136];
    __shared__ _Float16 Blo[64][136];
    const int tid = threadIdx.x;
    const int m0 = blockIdx.x << 7, n0 = blockIdx.y << 6;  // m-tile 128

    const int wv = tid >> 6, lane = tid & 63;
    const int fm = lane & 15, fq = lane >> 4;
    const float* abase0 = A + (size_t)(m0 + (wv << 4) + fm) * 256;
    const float* abase1 = abase0 + (size_t)64 * 256;       // second m-group

    const int srow = tid >> 4;            // 0..15
    const int skl  = (tid & 15) << 3;     // k-local 0..120 step 8

    f32x4 acc[2][4];
    #pragma unroll
    for (int g = 0; g < 2; ++g)
        #pragma unroll
        for (int cb = 0; cb < 4; ++cb) {
            acc[g][cb][0]=0.f; acc[g][cb][1]=0.f;
            acc[g][cb][2]=0.f; acc[g][cb][3]=0.f;
        }

    // A prefetch k-step 0, both groups
    float4 p00 = *(const float4*)(abase0 + (fq << 3));
    float4 p01 = *(const float4*)(abase0 + (fq << 3) + 4);
    float4 p10 = *(const float4*)(abase1 + (fq << 3));
    float4 p11 = *(const float4*)(abase1 + (fq << 3) + 4);

    #pragma unroll
    for (int h = 0; h < 2; ++h) {
        if (h) __syncthreads();          // previous half's reads done before restage
        #pragma unroll
        for (int p = 0; p < 4; ++p) {
            const int n = (p << 4) + srow;
            const size_t off = (size_t)(n0 + n) * 256 + (h << 7) + skl;
            *(f16x8*)&Bhi[n][skl] = *(const f16x8*)(Whi + off);
            *(f16x8*)&Blo[n][skl] = *(const f16x8*)(Wlo + off);
        }
        __syncthreads();

        #pragma unroll
        for (int kb = 0; kb < 4; ++kb) {
            const int ks = (h << 2) + kb;
            // prefetch next k-step, both groups (regs survive restage barrier)
            float4 n00 = p00, n01 = p01, n10 = p10, n11 = p11;
            if (ks < 7) {
                const float* np0 = abase0 + ((ks + 1) << 5) + (fq << 3);
                const float* np1 = abase1 + ((ks + 1) << 5) + (fq << 3);
                n00 = *(const float4*)np0;
                n01 = *(const float4*)(np0 + 4);
                n10 = *(const float4*)np1;
                n11 = *(const float4*)(np1 + 4);
            }
            // convert both groups to split-f16
            f16x8 Ah0, Al0, Ah1, Al1;
            {
                const float ae0[8] = {p00.x,p00.y,p00.z,p00.w,p01.x,p01.y,p01.z,p01.w};
                const float ae1[8] = {p10.x,p10.y,p10.z,p10.w,p11.x,p11.y,p11.z,p11.w};
                #pragma unroll
                for (int j = 0; j < 8; ++j) {
                    const _Float16 h0 = (_Float16)ae0[j];
                    const _Float16 h1 = (_Float16)ae1[j];
                    Ah0[j] = h0; Al0[j] = (_Float16)(ae0[j] - (float)h0);
                    Ah1[j] = h1; Al1[j] = (_Float16)(ae1[j] - (float)h1);
                }
            }
            #pragma unroll
            for (int cb = 0; cb < 4; ++cb) {
                f16x8 Bh = *(const f16x8*)&Bhi[(cb << 4) + fm][(kb << 5) + (fq << 3)];
                f16x8 Bl = *(const f16x8*)&Blo[(cb << 4) + fm][(kb << 5) + (fq << 3)];
                acc[0][cb] = __builtin_amdgcn_mfma_f32_16x16x32_f16(Ah0, Bh, acc[0][cb], 0, 0, 0);
                acc[1][cb] = __builtin_amdgcn_mfma_f32_16x16x32_f16(Ah1, Bh, acc[1][cb], 0, 0, 0);
                acc[0][cb] = __builtin_amdgcn_mfma_f32_16x16x32_f16(Al0, Bh, acc[0][cb], 0, 0, 0);
                acc[1][cb] = __builtin_amdgcn_mfma_f32_16x16x32_f16(Al1, Bh, acc[1][cb], 0, 0, 0);
                acc[0][cb] = __builtin_amdgcn_mfma_f32_16x16x32_f16(Ah0, Bl, acc[0][cb], 0, 0, 0);
                acc[1][cb] = __builtin_amdgcn_mfma_f32_16x16x32_f16(Ah1, Bl, acc[1][cb], 0, 0, 0);
            }
            p00 = n00; p01 = n01; p10 = n10; p11 = n11;
        }
    }

    if (vf16) {
        _Float16* Cv = (_Float16*)C;
        #pragma unroll
        for (int g = 0; g < 2; ++g)
            #pragma unroll
            for (int cb = 0; cb < 4; ++cb) {
                const float bb = bias[n0 + (cb << 4) + fm];
                #pragma unroll
                for (int i = 0; i < 4; ++i)
                    Cv[(size_t)(m0 + (g << 6) + (wv << 4) + (fq << 2) + i) * 256
                       + n0 + (cb << 4) + fm] = (_Float16)(acc[g][cb][i] + bb);
            }
    } else {
        #pragma unroll
        for (int g = 0; g < 2; ++g)
            #pragma unroll
            for (int cb = 0; cb < 4; ++cb) {
                const float bb = bias[n0 + (cb << 4) + fm];
                #pragma unroll
                for (int i = 0; i < 4; ++i)
                    C[(size_t)(m0 + (g << 6) + (wv << 4) + (fq << 2) + i) * 256
                      + n0 + (cb << 4) + fm] = acc[g][cb][i] + bb;
            }
    }
}

__global__ __attribute__((amdgpu_waves_per_eu(4, 4)))
__launch_bounds__(256) void gemmQKV(
    const float* __restrict__ x, const float* __restrict__ y,
    const _Float16* __restrict__ WP,
    const float* __restrict__ bq, const float* __restrict__ bk,
    const float* __restrict__ bv,
    float* __restrict__ Q, float* __restrict__ K, float* __restrict__ Vf)
{
    const int z = blockIdx.z;
    const float* A = (z == 0) ? x  : y;
    const _Float16* Whi = WP + ((size_t)z << 17);
    const _Float16* Wlo = Whi + 65536;
    const float* b = (z == 0) ? bq : (z == 1) ? bk : bv;
    float*       C = (z == 0) ? Q  : (z == 1) ? K  : Vf;
    gemm_mfma(A, Whi, Wlo, b, C, z == 2);
}

__global__ __attribute__((amdgpu_waves_per_eu(4, 4)))
__launch_bounds__(256) void gemmOut(
    const float* __restrict__ A, const _Float16* __restrict__ WP,
    const float* __restrict__ b, float* __restrict__ C)
{
    const _Float16* Whi = WP + ((size_t)3 << 17);
    const _Float16* Wlo = Whi + 65536;
    gemm_mfma(A, Whi, Wlo, b, C, 0);
}

// ---------------------------------------------------------------------------
// Attention — EXACT R18 body (181-183 us, proven 5x). CONVERGED: occupancy up
// (R13) -> spills; smarter median (R15/R19) -> slower; barrier removal via
// dbuf (R21) -> occupancy loss. Rules: no added loop-carried live values;
// median untouched; 3-barrier / 3-block structure is the optimum.
// ---------------------------------------------------------------------------
__device__ __forceinline__ float u2f(unsigned int m) {
    unsigned int x = (m & 0x80000000u) ? (m ^ 0x80000000u) : ~m;
    return __uint_as_float(x);
}
__device__ __forceinline__ unsigned int f2u(float f) {
    unsigned int x = __float_as_uint(f);
    return (x & 0x80000000u) ? ~x : (x | 0x80000000u);
}

// 64-lane reductions via DPP: row_shr 1/2/4/8 + row_bcast15/31, ~6 VALU ops.
__device__ __forceinline__ float wred_sum(float x) {
    x += __int_as_float(__builtin_amdgcn_update_dpp(0, __float_as_int(x), 0x111, 0xF, 0xF, true));
    x += __int_as_float(__builtin_amdgcn_update_dpp(0, __float_as_int(x), 0x112, 0xF, 0xF, true));
    x += __int_as_float(__builtin_amdgcn_update_dpp(0, __float_as_int(x), 0x114, 0xF, 0xF, true));
    x += __int_as_float(__builtin_amdgcn_update_dpp(0, __float_as_int(x), 0x118, 0xF, 0xF, true));
    x += __int_as_float(__builtin_amdgcn_update_dpp(0, __float_as_int(x), 0x142, 0xF, 0xF, true));
    x += __int_as_float(__builtin_amdgcn_update_dpp(0, __float_as_int(x), 0x143, 0xF, 0xF, true));
    return __int_as_float(__builtin_amdgcn_readlane(__float_as_int(x), 63));
}
__device__ __forceinline__ float wred_min(float x) {
    const int IDENT = 0x7f7fffff;  // +FLT_MAX
    x = fminf(x, __int_as_float(__builtin_amdgcn_update_dpp(IDENT, __float_as_int(x), 0x111, 0xF, 0xF, false)));
    x = fminf(x, __int_as_float(__builtin_amdgcn_update_dpp(IDENT, __float_as_int(x), 0x112, 0xF, 0xF, false)));
    x = fminf(x, __int_as_float(__builtin_amdgcn_update_dpp(IDENT, __float_as_int(x), 0x114, 0xF, 0xF, false)));
    x = fminf(x, __int_as_float(__builtin_amdgcn_update_dpp(IDENT, __float_as_int(x), 0x118, 0xF, 0xF, false)));
    x = fminf(x, __int_as_float(__builtin_amdgcn_update_dpp(IDENT, __float_as_int(x), 0x142, 0xF, 0xF, false)));
    x = fminf(x, __int_as_float(__builtin_amdgcn_update_dpp(IDENT, __float_as_int(x), 0x143, 0xF, 0xF, false)));
    return __int_as_float(__builtin_amdgcn_readlane(__float_as_int(x), 63));
}
__device__ __forceinline__ float wred_max(float x) {
    const int IDENT = (int)0xff7fffff;  // -FLT_MAX
    x = fmaxf(x, __int_as_float(__builtin_amdgcn_update_dpp(IDENT, __float_as_int(x), 0x111, 0xF, 0xF, false)));
    x = fmaxf(x, __int_as_float(__builtin_amdgcn_update_dpp(IDENT, __float_as_int(x), 0x112, 0xF, 0xF, false)));
    x = fmaxf(x, __int_as_float(__builtin_amdgcn_update_dpp(IDENT, __float_as_int(x), 0x114, 0xF, 0xF, false)));
    x = fmaxf(x, __int_as_float(__builtin_amdgcn_update_dpp(IDENT, __float_as_int(x), 0x118, 0xF, 0xF, false)));
    x = fmaxf(x, __int_as_float(__builtin_amdgcn_update_dpp(IDENT, __float_as_int(x), 0x142, 0xF, 0xF, false)));
    x = fmaxf(x, __int_as_float(__builtin_amdgcn_update_dpp(IDENT, __float_as_int(x), 0x143, 0xF, 0xF, false)));
    return __int_as_float(__builtin_amdgcn_readlane(__float_as_int(x), 63));
}

__global__ __attribute__((amdgpu_waves_per_eu(6, 6)))
__launch_bounds__(512) void attn(
    const float* __restrict__ Qb, const float* __restrict__ Kb,
    const _Float16* __restrict__ Vb, float* __restrict__ Ob)
{
    __shared__ union {
        float    Ssc[8][1028];     // pad 1028: phase-1 C-writes hit 32 banks
        _Float16 Vt[16][1032];     // V staging (pre-loop only)
    } U;
    __shared__ float part[1024];   // [8 waves][8 rows][16 d]
    __shared__ float sums[2][8];

    const int tid  = threadIdx.x;
    const int wave = tid >> 6, lane = tid & 63;
    const int head = blockIdx.x, grp = blockIdx.y;
    const float*    Qh = Qb + ((size_t)head << 14);
    const float*    Kh = Kb + ((size_t)head << 14);
    const _Float16* Vh = Vb + ((size_t)head << 14);
    const int fm = lane & 15, fq = lane >> 4;

    // ---- stage V transposed (already f16), grab register fragments ----
    for (int i = tid; i < 4096; i += 512) {
        f16x4 v = ((const f16x4*)Vh)[i];
        const int k = i >> 2, d0 = (i & 3) << 2;
        U.Vt[d0 + 0][k] = v[0];
        U.Vt[d0 + 1][k] = v[1];
        U.Vt[d0 + 2][k] = v[2];
        U.Vt[d0 + 3][k] = v[3];
    }
    __syncthreads();
    f16x8 Vf[4];
    #pragma unroll
    for (int kb = 0; kb < 4; ++kb)
        Vf[kb] = *(const f16x8*)&U.Vt[fm][(((wave << 2) + kb) << 5) + (fq << 3)];

    // ---- persistent K fragments packed [Bh|Bl], K pre-scaled by 1/8 ----
    f16x8 Bp[8];
    #pragma unroll
    for (int kb = 0; kb < 8; ++kb) {
        const int krow = (wave << 7) + (kb << 4) + fm;
        float4 kv = *(const float4*)(Kh + ((size_t)krow << 4) + (fq << 2));
        const float ke[4] = {kv.x * 0.125f, kv.y * 0.125f,
                             kv.z * 0.125f, kv.w * 0.125f};
        #pragma unroll
        for (int j = 0; j < 4; ++j) {
            _Float16 h = (_Float16)ke[j];
            Bp[kb][j]     = h;
            Bp[kb][j + 4] = (_Float16)(ke[j] - (float)h);
        }
    }
    __syncthreads();               // Vf reads done before Ssc overwrites Vt

    const int cstart = (grp * 128) / 6;
    const int cend   = ((grp + 1) * 128) / 6;

    for (int chunk = cstart; chunk < cend; ++chunk) {
        const int qbase = chunk << 3;
        const int sb = chunk & 1;

        // ---- phase 1: S = Q K^T/8, 2 packed MFMAs per 16-col tile ----
        f16x8 A1, A2;
        {
            const int arow = qbase + (fm & 7);
            float4 qv = *(const float4*)(Qh + ((size_t)arow << 4) + (fq << 2));
            const float qe[4] = {qv.x, qv.y, qv.z, qv.w};
            #pragma unroll
            for (int j = 0; j < 4; ++j) {
                _Float16 h = (_Float16)qe[j];
                A1[j] = h; A1[j + 4] = h;
                A2[j] = (_Float16)(qe[j] - (float)h);
                A2[j + 4] = (_Float16)0.f;
            }
        }
        #pragma unroll
        for (int kb = 0; kb < 8; ++kb) {
            f32x4 c = {0.f, 0.f, 0.f, 0.f};
            c = __builtin_amdgcn_mfma_f32_16x16x32_f16(A1, Bp[kb], c, 0, 0, 0);
            c = __builtin_amdgcn_mfma_f32_16x16x32_f16(A2, Bp[kb], c, 0, 0, 0);
            if (fq < 2) {
                const int col = (wave << 7) + (kb << 4) + fm;
                #pragma unroll
                for (int i = 0; i < 4; ++i)
                    U.Ssc[(fq << 2) + i][col] = c[i];
            }
        }
        __syncthreads();   // B1: scores visible

        // ---- wave w owns row w; contiguous b128 reads ----
        float s[16];
        #pragma unroll
        for (int b = 0; b < 4; ++b) {
            f32x4 v = *(const f32x4*)&U.Ssc[wave][(b << 8) + (lane << 2)];
            s[(b << 2) + 0] = v.x; s[(b << 2) + 1] = v.y;
            s[(b << 2) + 2] = v.z; s[(b << 2) + 3] = v.w;
        }
        // (B2 deleted: P row w is written into Ssc row w, which only this
        //  wave has consumed; intra-wave DS ops are in-order.)

        // ---- phase 2: exact lower median (512th smallest) ----
        float mn = 0.f, sq = 0.f;
        #pragma unroll
        for (int j = 0; j < 16; ++j) { mn += s[j]; sq += s[j] * s[j]; }
        mn = wred_sum(mn);
        sq = wred_sum(sq);
        mn *= (1.0f / 1024.0f);
        const float var  = fmaxf(sq * (1.0f / 1024.0f) - mn * mn, 1e-12f);
        const float step = __builtin_sqrtf(var) * 0.0024479f; // sigma*sqrt(2pi)/1024

        unsigned int lo = 0x00800000u, hi = 0xFF7FFFFFu;
        int cl = 0, ch = 1024;
        float vL = -3.4e38f, vH = 3.4e38f;
        float t = mn, medf = 0.f;
        int found = 0;
        for (int pass = 0; pass < 64 && !found; ++pass) {
            int cnt = 0;
            #pragma unroll
            for (int j = 0; j < 16; ++j)
                cnt += __popcll(__ballot(s[j] <= t));
            const unsigned int tc = f2u(t);
            if (cnt >= 512) { hi = tc; ch = cnt; vH = t; }
            else            { lo = tc + 1; cl = cnt; vL = t; }

            if (cl == 511) {               // 512th = min{s > vL}
                float c = 3.4e38f;
                #pragma unroll
                for (int j = 0; j < 16; ++j)
                    c = fminf(c, (s[j] > vL) ? s[j] : 3.4e38f);
                medf = wred_min(c); found = 1;
            } else if (ch == 512) {        // 512th = max{s <= vH}
                float c = -3.4e38f;
                #pragma unroll
                for (int j = 0; j < 16; ++j)
                    c = fmaxf(c, (s[j] <= vH) ? s[j] : -3.4e38f);
                medf = wred_max(c); found = 1;
            } else if (cl == 510) {
                // m1 = 511th = min{s > vL}; dup-safe step to 512th
                float m1 = 3.4e38f;
                #pragma unroll
                for (int j = 0; j < 16; ++j)
                    m1 = fminf(m1, (s[j] > vL) ? s[j] : 3.4e38f);
                m1 = wred_min(m1);
                int c1 = 0;
                #pragma unroll
                for (int j = 0; j < 16; ++j)
                    c1 += __popcll(__ballot(s[j] <= m1));
                if (c1 >= 512) { medf = m1; }
                else {
                    float c2 = 3.4e38f;
                    #pragma unroll
                    for (int j = 0; j < 16; ++j)
                        c2 = fminf(c2, (s[j] > m1) ? s[j] : 3.4e38f);
                    medf = wred_min(c2);
                }
                found = 1;
            } else if (ch == 513) {
                // m1 = 513th = max{s <= vH}; dup-safe step back to 512th
                float m1 = -3.4e38f;
                #pragma unroll
                for (int j = 0; j < 16; ++j)
                    m1 = fmaxf(m1, (s[j] <= vH) ? s[j] : -3.4e38f);
                m1 = wred_max(m1);
                int c1 = 0;
                #pragma unroll
                for (int j = 0; j < 16; ++j)
                    c1 += __popcll(__ballot(s[j] < m1));
                if (c1 <= 511) { medf = m1; }
                else {
                    float c2 = -3.4e38f;
                    #pragma unroll
                    for (int j = 0; j < 16; ++j)
                        c2 = fmaxf(c2, (s[j] < m1) ? s[j] : -3.4e38f);
                    medf = wred_max(c2);
                }
                found = 1;
            } else if (lo >= hi) {
                medf = u2f(lo); found = 1;   // heavy ties: code-exact
            } else {
                float tn = t + (511.5f - (float)cnt) * step;
                bool ok = (tn > vL) && (tn < vH);
                if (pass >= 5 && (pass & 1)) ok = false;   // forced bisection
                t = ok ? tn : u2f(lo + ((hi - lo) >> 1));
            }
        }
        if (!found) medf = u2f(lo);

        // ---- phase 2.5: masked exp, f16 round, row-sum, P into own Ssc row ----
        _Float16* Pw = (_Float16*)&U.Ssc[wave][0];
        float sum = 0.f;
        #pragma unroll
        for (int b = 0; b < 4; ++b) {
            f16x4 hv;
            #pragma unroll
            for (int jj = 0; jj < 4; ++jj) {
                float e = (s[(b << 2) + jj] > medf) ? __expf(s[(b << 2) + jj]) : 0.f;
                _Float16 h = (_Float16)e;
                hv[jj] = h;
                sum += (float)h;
            }
            *(f16x4*)&Pw[(b << 8) + (lane << 2)] = hv;
        }
        sum = wred_sum(sum);
        if (lane == 0) sums[sb][wave] = sum;
        __syncthreads();   // B3: P + sums visible

        // ---- phase 3: PV via MFMA; A=P rows (dup fm&7), B=V registers ----
        f32x4 acc = {0.f, 0.f, 0.f, 0.f};
        const _Float16* Pr = (const _Float16*)&U.Ssc[fm & 7][0] + (fq << 3);
        #pragma unroll
        for (int kb = 0; kb < 4; ++kb) {
            f16x8 a = *(const f16x8*)(Pr + ((((wave << 2) + kb)) << 5));
            acc = __builtin_amdgcn_mfma_f32_16x16x32_f16(a, Vf[kb], acc, 0, 0, 0);
        }
        if (lane < 32) {   // C rows 0-7 live in quads 0-1
            #pragma unroll
            for (int i = 0; i < 4; ++i)
                part[(wave << 7) + (((fq << 2) + i) << 4) + fm] = acc[i];
        }
        __syncthreads();   // B4: partials visible (also: P reads done)

        // ---- reduce 8 partials + store; rotate active waves by chunk ----
        const int rw = (wave - chunk) & 7;
        if (rw < 2) {
            const int t2 = (rw << 6) + lane;
            const int r = t2 >> 4, d = t2 & 15;
            float o = 0.f;
            #pragma unroll
            for (int w = 0; w < 8; ++w) o += part[(w << 7) + t2];
            const float inv = 1.0f / sums[sb][r];
            const int q = qbase + r;
            const int h = head >> 3, bp = head & 7;
            float* dst = Ob + (((size_t)(h >> 1)) << 18)
                            + ((size_t)(((h & 1) << 9) + (q >> 1)) << 8)
                            + ((q & 1) << 7) + (bp << 4) + d;
            *dst = o * inv;
        }
    }
}

// ---------------------------------------------------------------------------
extern "C" void kernel_launch(void* const* d_in, const int* in_sizes, int n_in,
                              void* d_out, int out_size, void* d_ws, size_t ws_size,
                              hipStream_t stream) {
    const float* x  = (const float*)d_in[0];
    const float* y  = (const float*)d_in[1];
    const float* Wq = (const float*)d_in[2];
    const float* bq = (const float*)d_in[3];
    const float* Wk = (const float*)d_in[4];
    const float* bk = (const float*)d_in[5];
    const float* Wv = (const float*)d_in[6];
    const float* bv = (const float*)d_in[7];
    const float* Wo = (const float*)d_in[8];
    const float* bo = (const float*)d_in[9];
    float* out = (float*)d_out;

    float*     Q  = (float*)d_ws;                       // 2M floats
    float*     K  = Q + 2097152;                        // 2M floats
    _Float16*  V  = (_Float16*)(K + 2097152);           // 2M f16 (1M floats)
    float*     AO = (float*)d_ws + 5242880;             // 2M floats
    _Float16*  WP = (_Float16*)((float*)d_ws + 7340032);// 512K f16 (256K floats)

    prepW<<<dim3(16, 4), dim3(256), 0, stream>>>(Wq, Wk, Wv, Wo, WP);
    gemmQKV<<<dim3(64, 4, 3), dim3(256), 0, stream>>>(x, y, WP, bq, bk, bv,
                                                      Q, K, (float*)V);
    attn<<<dim3(128, 6), dim3(512), 0, stream>>>(Q, K, V, AO);
    gemmOut<<<dim3(64, 4), dim3(256), 0, stream>>>(AO, WP, bo, out);
}

// Round 13
// 260.359 us; speedup vs baseline: 1.0530x; 1.0530x over previous
//
#include <hip/hip_runtime.h>
#include <stdint.h>

// B=8, S=1024, D_MODEL=256, dk=dv=16, 128 pseudo-heads of 1024x16.
// ws layout (floats): Q[2M] | K[2M] | VT(f16, 1M floats) | AO[2M] | Wplanes[256K]
// VT: V stored TRANSPOSED per head: VT[head][d=16][k=1024] f16.
// Wplanes: 4 matrices x { hi[256][256], lo[256][256] } f16, layout [n][k].

typedef _Float16 f16x8 __attribute__((ext_vector_type(8)));
typedef _Float16 f16x4 __attribute__((ext_vector_type(4)));
typedef float    f32x4 __attribute__((ext_vector_type(4)));

// ---------------------------------------------------------------------------
// prepW: one-shot transpose + split-f16 conversion of the four weight
// matrices (f32 [k][n] -> f16 hi/lo planes [n][k]). Coalesced via LDS tiles.
// ---------------------------------------------------------------------------
__global__ __launch_bounds__(256) void prepW(
    const float* __restrict__ Wq, const float* __restrict__ Wk,
    const float* __restrict__ Wv, const float* __restrict__ Wo,
    _Float16* __restrict__ P)
{
    __shared__ float T[64][65];
    const int mat = blockIdx.y;
    const float* W = (mat == 0) ? Wq : (mat == 1) ? Wk : (mat == 2) ? Wv : Wo;
    const int tk = blockIdx.x >> 2, tn = blockIdx.x & 3;   // 4x4 tiles of 64
    const int t  = threadIdx.x;
    const int cl = t & 63, rg = t >> 6;

    #pragma unroll
    for (int r = 0; r < 16; ++r) {
        const int k = (rg << 4) + r;                       // local k
        T[k][cl] = W[(size_t)((tk << 6) + k) * 256 + (tn << 6) + cl];
    }
    __syncthreads();
    _Float16* hi = P + ((size_t)mat << 17);                // 2*65536 f16 per mat
    _Float16* lo = hi + 65536;
    #pragma unroll
    for (int r = 0; r < 16; ++r) {
        const int n = (rg << 4) + r;                       // local n
        const float v = T[cl][n];                          // transposed read
        const _Float16 h = (_Float16)v;
        const size_t o = (size_t)((tn << 6) + n) * 256 + (tk << 6) + cl;
        hi[o] = h;
        lo[o] = (_Float16)(v - (float)h);
    }
}

// ---------------------------------------------------------------------------
// Split-f16 MFMA GEMM: C[8192x256] = A @ W + bias.  (R20 structure, banked)
// 512-thread blocks, m-tile 128, 34.8 KB staging.
// R24: vf16 path writes V TRANSPOSED (VT[head][d][k], f16x4 packed stores:
// the 4 cb-outputs of a thread at fixed (d,i) are consecutive k's).
// ---------------------------------------------------------------------------
__device__ __forceinline__ void gemm_mfma(const float* __restrict__ A,
                                          const _Float16* __restrict__ Whi,
                                          const _Float16* __restrict__ Wlo,
                                          const float* __restrict__ bias,
                                          float* __restrict__ C, int vf16)
{
    __shared__ _Float16 Bhi[64][136];
    __shared__ _Float16 Blo[64][136];
    const int tid = threadIdx.x;
    const int m0 = blockIdx.x << 7, n0 = blockIdx.y << 6;

    const int wv = tid >> 6, lane = tid & 63;
    const int fm = lane & 15, fq = lane >> 4;
    const int arow = m0 + (wv << 4) + fm;
    const float* abase = A + (size_t)arow * 256;

    // staging: 512 threads, 16 lanes/row (16B each), 32 rows/pass, 2 passes
    const int srow = tid >> 4;            // 0..31
    const int skl  = (tid & 15) << 3;     // k-local 0..120 step 8

    f32x4 acc[4];
    #pragma unroll
    for (int cb = 0; cb < 4; ++cb) { acc[cb][0]=0.f; acc[cb][1]=0.f; acc[cb][2]=0.f; acc[cb][3]=0.f; }

    float4 a0 = *(const float4*)(abase + (fq << 3));
    float4 a1 = *(const float4*)(abase + (fq << 3) + 4);

    #pragma unroll
    for (int h = 0; h < 2; ++h) {
        if (h) __syncthreads();          // previous half's reads done before restage
        #pragma unroll
        for (int p = 0; p < 2; ++p) {
            const int n = (p << 5) + srow;
            const size_t off = (size_t)(n0 + n) * 256 + (h << 7) + skl;
            *(f16x8*)&Bhi[n][skl] = *(const f16x8*)(Whi + off);
            *(f16x8*)&Blo[n][skl] = *(const f16x8*)(Wlo + off);
        }
        __syncthreads();

        #pragma unroll
        for (int kb = 0; kb < 4; ++kb) {
            const int ks = (h << 2) + kb;
            float4 n0v = a0, n1v = a1;
            if (ks < 7) {
                const float* np = abase + ((ks + 1) << 5) + (fq << 3);
                n0v = *(const float4*)np;
                n1v = *(const float4*)(np + 4);
            }
            const float ae[8] = {a0.x, a0.y, a0.z, a0.w, a1.x, a1.y, a1.z, a1.w};
            f16x8 Ah, Al;
            #pragma unroll
            for (int j = 0; j < 8; ++j) {
                const _Float16 hh = (_Float16)ae[j];
                Ah[j] = hh;
                Al[j] = (_Float16)(ae[j] - (float)hh);
            }
            #pragma unroll
            for (int cb = 0; cb < 4; ++cb) {
                f16x8 Bh = *(const f16x8*)&Bhi[(cb << 4) + fm][(kb << 5) + (fq << 3)];
                f16x8 Bl = *(const f16x8*)&Blo[(cb << 4) + fm][(kb << 5) + (fq << 3)];
                acc[cb] = __builtin_amdgcn_mfma_f32_16x16x32_f16(Ah, Bh, acc[cb], 0, 0, 0);
                acc[cb] = __builtin_amdgcn_mfma_f32_16x16x32_f16(Al, Bh, acc[cb], 0, 0, 0);
                acc[cb] = __builtin_amdgcn_mfma_f32_16x16x32_f16(Ah, Bl, acc[cb], 0, 0, 0);
            }
            a0 = n0v; a1 = n1v;
        }
    }

    if (vf16) {
        // transposed V store: VT[head][d][k], head=m>>6, d=n&15=fm,
        // k=((m&63)<<4)+(n>>4). cb gives consecutive k -> f16x4 per (i).
        _Float16* Vt = (_Float16*)C;
        float bb[4];
        #pragma unroll
        for (int cb = 0; cb < 4; ++cb) bb[cb] = bias[n0 + (cb << 4) + fm];
        #pragma unroll
        for (int i = 0; i < 4; ++i) {
            const int m = m0 + (wv << 4) + (fq << 2) + i;
            f16x4 v;
            #pragma unroll
            for (int cb = 0; cb < 4; ++cb)
                v[cb] = (_Float16)(acc[cb][i] + bb[cb]);
            const size_t o = ((size_t)(m >> 6) << 14) + ((size_t)fm << 10)
                           + ((m & 63) << 4) + (n0 >> 4);
            *(f16x4*)&Vt[o] = v;
        }
    } else {
        #pragma unroll
        for (int cb = 0; cb < 4; ++cb) {
            const float bb = bias[n0 + (cb << 4) + fm];
            #pragma unroll
            for (int i = 0; i < 4; ++i)
                C[(size_t)(m0 + (wv << 4) + (fq << 2) + i) * 256
                  + n0 + (cb << 4) + fm] = acc[cb][i] + bb;
        }
    }
}

__global__ __attribute__((amdgpu_waves_per_eu(6, 6)))
__launch_bounds__(512) void gemmQKV(
    const float* __restrict__ x, const float* __restrict__ y,
    const _Float16* __restrict__ WP,
    const float* __restrict__ bq, const float* __restrict__ bk,
    const float* __restrict__ bv,
    float* __restrict__ Q, float* __restrict__ K, float* __restrict__ Vf)
{
    const int z = blockIdx.z;
    const float* A = (z == 0) ? x  : y;
    const _Float16* Whi = WP + ((size_t)z << 17);
    const _Float16* Wlo = Whi + 65536;
    const float* b = (z == 0) ? bq : (z == 1) ? bk : bv;
    float*       C = (z == 0) ? Q  : (z == 1) ? K  : Vf;
    gemm_mfma(A, Whi, Wlo, b, C, z == 2);
}

__global__ __attribute__((amdgpu_waves_per_eu(6, 6)))
__launch_bounds__(512) void gemmOut(
    const float* __restrict__ A, const _Float16* __restrict__ WP,
    const float* __restrict__ b, float* __restrict__ C)
{
    const _Float16* Whi = WP + ((size_t)3 << 17);
    const _Float16* Wlo = Whi + 65536;
    gemm_mfma(A, Whi, Wlo, b, C, 0);
}

// ---------------------------------------------------------------------------
// Attention — R18 body except V: occupancy has been register-limited (~4.5
// waves/SIMD; unified VGPR+AGPR file, persistent Bp+Vf fragments), NOT
// LDS-limited. R24: Vf de-registerized — V read per chunk from global VT
// (L2-hot 32KB/head) inside the PV phase; pre-loop V staging + LDS union +
// both pre-loop barriers deleted. V bits identical. Rules: median untouched;
// no added loop-carried live values (Vf becomes phase-local: a reduction).
// ---------------------------------------------------------------------------
__device__ __forceinline__ float u2f(unsigned int m) {
    unsigned int x = (m & 0x80000000u) ? (m ^ 0x80000000u) : ~m;
    return __uint_as_float(x);
}
__device__ __forceinline__ unsigned int f2u(float f) {
    unsigned int x = __float_as_uint(f);
    return (x & 0x80000000u) ? ~x : (x | 0x80000000u);
}

// 64-lane reductions via DPP: row_shr 1/2/4/8 + row_bcast15/31, ~6 VALU ops.
__device__ __forceinline__ float wred_sum(float x) {
    x += __int_as_float(__builtin_amdgcn_update_dpp(0, __float_as_int(x), 0x111, 0xF, 0xF, true));
    x += __int_as_float(__builtin_amdgcn_update_dpp(0, __float_as_int(x), 0x112, 0xF, 0xF, true));
    x += __int_as_float(__builtin_amdgcn_update_dpp(0, __float_as_int(x), 0x114, 0xF, 0xF, true));
    x += __int_as_float(__builtin_amdgcn_update_dpp(0, __float_as_int(x), 0x118, 0xF, 0xF, true));
    x += __int_as_float(__builtin_amdgcn_update_dpp(0, __float_as_int(x), 0x142, 0xF, 0xF, true));
    x += __int_as_float(__builtin_amdgcn_update_dpp(0, __float_as_int(x), 0x143, 0xF, 0xF, true));
    return __int_as_float(__builtin_amdgcn_readlane(__float_as_int(x), 63));
}
__device__ __forceinline__ float wred_min(float x) {
    const int IDENT = 0x7f7fffff;  // +FLT_MAX
    x = fminf(x, __int_as_float(__builtin_amdgcn_update_dpp(IDENT, __float_as_int(x), 0x111, 0xF, 0xF, false)));
    x = fminf(x, __int_as_float(__builtin_amdgcn_update_dpp(IDENT, __float_as_int(x), 0x112, 0xF, 0xF, false)));
    x = fminf(x, __int_as_float(__builtin_amdgcn_update_dpp(IDENT, __float_as_int(x), 0x114, 0xF, 0xF, false)));
    x = fminf(x, __int_as_float(__builtin_amdgcn_update_dpp(IDENT, __float_as_int(x), 0x118, 0xF, 0xF, false)));
    x = fminf(x, __int_as_float(__builtin_amdgcn_update_dpp(IDENT, __float_as_int(x), 0x142, 0xF, 0xF, false)));
    x = fminf(x, __int_as_float(__builtin_amdgcn_update_dpp(IDENT, __float_as_int(x), 0x143, 0xF, 0xF, false)));
    return __int_as_float(__builtin_amdgcn_readlane(__float_as_int(x), 63));
}
__device__ __forceinline__ float wred_max(float x) {
    const int IDENT = (int)0xff7fffff;  // -FLT_MAX
    x = fmaxf(x, __int_as_float(__builtin_amdgcn_update_dpp(IDENT, __float_as_int(x), 0x111, 0xF, 0xF, false)));
    x = fmaxf(x, __int_as_float(__builtin_amdgcn_update_dpp(IDENT, __float_as_int(x), 0x112, 0xF, 0xF, false)));
    x = fmaxf(x, __int_as_float(__builtin_amdgcn_update_dpp(IDENT, __float_as_int(x), 0x114, 0xF, 0xF, false)));
    x = fmaxf(x, __int_as_float(__builtin_amdgcn_update_dpp(IDENT, __float_as_int(x), 0x118, 0xF, 0xF, false)));
    x = fmaxf(x, __int_as_float(__builtin_amdgcn_update_dpp(IDENT, __float_as_int(x), 0x142, 0xF, 0xF, false)));
    x = fmaxf(x, __int_as_float(__builtin_amdgcn_update_dpp(IDENT, __float_as_int(x), 0x143, 0xF, 0xF, false)));
    return __int_as_float(__builtin_amdgcn_readlane(__float_as_int(x), 63));
}

__global__ __attribute__((amdgpu_waves_per_eu(6, 6)))
__launch_bounds__(512) void attn(
    const float* __restrict__ Qb, const float* __restrict__ Kb,
    const _Float16* __restrict__ Vb, float* __restrict__ Ob)
{
    __shared__ float Ssc[8][1028];  // pad 1028: phase-1 C-writes hit 32 banks
    __shared__ float part[1024];    // [8 waves][8 rows][16 d]
    __shared__ float sums[2][8];

    const int tid  = threadIdx.x;
    const int wave = tid >> 6, lane = tid & 63;
    const int head = blockIdx.x, grp = blockIdx.y;
    const float*    Qh = Qb + ((size_t)head << 14);
    const float*    Kh = Kb + ((size_t)head << 14);
    const _Float16* Vh = Vb + ((size_t)head << 14);   // VT[head][d][k]
    const int fm = lane & 15, fq = lane >> 4;

    // ---- persistent K fragments packed [Bh|Bl], K pre-scaled by 1/8 ----
    f16x8 Bp[8];
    #pragma unroll
    for (int kb = 0; kb < 8; ++kb) {
        const int krow = (wave << 7) + (kb << 4) + fm;
        float4 kv = *(const float4*)(Kh + ((size_t)krow << 4) + (fq << 2));
        const float ke[4] = {kv.x * 0.125f, kv.y * 0.125f,
                             kv.z * 0.125f, kv.w * 0.125f};
        #pragma unroll
        for (int j = 0; j < 4; ++j) {
            _Float16 h = (_Float16)ke[j];
            Bp[kb][j]     = h;
            Bp[kb][j + 4] = (_Float16)(ke[j] - (float)h);
        }
    }
    // per-chunk V fragment base: lane fm reads d-row fm, k-range of wave
    const _Float16* vfb = Vh + ((size_t)fm << 10) + (wave << 7) + (fq << 3);

    const int cstart = (grp * 128) / 6;
    const int cend   = ((grp + 1) * 128) / 6;

    for (int chunk = cstart; chunk < cend; ++chunk) {
        const int qbase = chunk << 3;
        const int sb = chunk & 1;

        // ---- phase 1: S = Q K^T/8, 2 packed MFMAs per 16-col tile ----
        f16x8 A1, A2;
        {
            const int arow = qbase + (fm & 7);
            float4 qv = *(const float4*)(Qh + ((size_t)arow << 4) + (fq << 2));
            const float qe[4] = {qv.x, qv.y, qv.z, qv.w};
            #pragma unroll
            for (int j = 0; j < 4; ++j) {
                _Float16 h = (_Float16)qe[j];
                A1[j] = h; A1[j + 4] = h;
                A2[j] = (_Float16)(qe[j] - (float)h);
                A2[j + 4] = (_Float16)0.f;
            }
        }
        #pragma unroll
        for (int kb = 0; kb < 8; ++kb) {
            f32x4 c = {0.f, 0.f, 0.f, 0.f};
            c = __builtin_amdgcn_mfma_f32_16x16x32_f16(A1, Bp[kb], c, 0, 0, 0);
            c = __builtin_amdgcn_mfma_f32_16x16x32_f16(A2, Bp[kb], c, 0, 0, 0);
            if (fq < 2) {
                const int col = (wave << 7) + (kb << 4) + fm;
                #pragma unroll
                for (int i = 0; i < 4; ++i)
                    Ssc[(fq << 2) + i][col] = c[i];
            }
        }
        __syncthreads();   // B1: scores visible

        // ---- wave w owns row w; contiguous b128 reads ----
        float s[16];
        #pragma unroll
        for (int b = 0; b < 4; ++b) {
            f32x4 v = *(const f32x4*)&Ssc[wave][(b << 8) + (lane << 2)];
            s[(b << 2) + 0] = v.x; s[(b << 2) + 1] = v.y;
            s[(b << 2) + 2] = v.z; s[(b << 2) + 3] = v.w;
        }
        // (B2 deleted: P row w is written into Ssc row w, which only this
        //  wave has consumed; intra-wave DS ops are in-order.)

        // ---- phase 2: exact lower median (512th smallest) ----
        float mn = 0.f, sq = 0.f;
        #pragma unroll
        for (int j = 0; j < 16; ++j) { mn += s[j]; sq += s[j] * s[j]; }
        mn = wred_sum(mn);
        sq = wred_sum(sq);
        mn *= (1.0f / 1024.0f);
        const float var  = fmaxf(sq * (1.0f / 1024.0f) - mn * mn, 1e-12f);
        const float step = __builtin_sqrtf(var) * 0.0024479f; // sigma*sqrt(2pi)/1024

        unsigned int lo = 0x00800000u, hi = 0xFF7FFFFFu;
        int cl = 0, ch = 1024;
        float vL = -3.4e38f, vH = 3.4e38f;
        float t = mn, medf = 0.f;
        int found = 0;
        for (int pass = 0; pass < 64 && !found; ++pass) {
            int cnt = 0;
            #pragma unroll
            for (int j = 0; j < 16; ++j)
                cnt += __popcll(__ballot(s[j] <= t));
            const unsigned int tc = f2u(t);
            if (cnt >= 512) { hi = tc; ch = cnt; vH = t; }
            else            { lo = tc + 1; cl = cnt; vL = t; }

            if (cl == 511) {               // 512th = min{s > vL}
                float c = 3.4e38f;
                #pragma unroll
                for (int j = 0; j < 16; ++j)
                    c = fminf(c, (s[j] > vL) ? s[j] : 3.4e38f);
                medf = wred_min(c); found = 1;
            } else if (ch == 512) {        // 512th = max{s <= vH}
                float c = -3.4e38f;
                #pragma unroll
                for (int j = 0; j < 16; ++j)
                    c = fmaxf(c, (s[j] <= vH) ? s[j] : -3.4e38f);
                medf = wred_max(c); found = 1;
            } else if (cl == 510) {
                // m1 = 511th = min{s > vL}; dup-safe step to 512th
                float m1 = 3.4e38f;
                #pragma unroll
                for (int j = 0; j < 16; ++j)
                    m1 = fminf(m1, (s[j] > vL) ? s[j] : 3.4e38f);
                m1 = wred_min(m1);
                int c1 = 0;
                #pragma unroll
                for (int j = 0; j < 16; ++j)
                    c1 += __popcll(__ballot(s[j] <= m1));
                if (c1 >= 512) { medf = m1; }
                else {
                    float c2 = 3.4e38f;
                    #pragma unroll
                    for (int j = 0; j < 16; ++j)
                        c2 = fminf(c2, (s[j] > m1) ? s[j] : 3.4e38f);
                    medf = wred_min(c2);
                }
                found = 1;
            } else if (ch == 513) {
                // m1 = 513th = max{s <= vH}; dup-safe step back to 512th
                float m1 = -3.4e38f;
                #pragma unroll
                for (int j = 0; j < 16; ++j)
                    m1 = fmaxf(m1, (s[j] <= vH) ? s[j] : -3.4e38f);
                m1 = wred_max(m1);
                int c1 = 0;
                #pragma unroll
                for (int j = 0; j < 16; ++j)
                    c1 += __popcll(__ballot(s[j] < m1));
                if (c1 <= 511) { medf = m1; }
                else {
                    float c2 = -3.4e38f;
                    #pragma unroll
                    for (int j = 0; j < 16; ++j)
                        c2 = fmaxf(c2, (s[j] < m1) ? s[j] : -3.4e38f);
                    medf = wred_max(c2);
                }
                found = 1;
            } else if (lo >= hi) {
                medf = u2f(lo); found = 1;   // heavy ties: code-exact
            } else {
                float tn = t + (511.5f - (float)cnt) * step;
                bool ok = (tn > vL) && (tn < vH);
                if (pass >= 5 && (pass & 1)) ok = false;   // forced bisection
                t = ok ? tn : u2f(lo + ((hi - lo) >> 1));
            }
        }
        if (!found) medf = u2f(lo);

        // ---- phase 2.5: masked exp, f16 round, row-sum, P into own Ssc row ----
        _Float16* Pw = (_Float16*)&Ssc[wave][0];
        float sum = 0.f;
        #pragma unroll
        for (int b = 0; b < 4; ++b) {
            f16x4 hv;
            #pragma unroll
            for (int jj = 0; jj < 4; ++jj) {
                float e = (s[(b << 2) + jj] > medf) ? __expf(s[(b << 2) + jj]) : 0.f;
                _Float16 h = (_Float16)e;
                hv[jj] = h;
                sum += (float)h;
            }
            *(f16x4*)&Pw[(b << 8) + (lane << 2)] = hv;
        }
        sum = wred_sum(sum);
        if (lane == 0) sums[sb][wave] = sum;
        __syncthreads();   // B3: P + sums visible

        // ---- phase 3: PV via MFMA; A=P rows, B=V fragments (per-chunk load,
        //      L2-hot; phase-local registers) ----
        f32x4 acc = {0.f, 0.f, 0.f, 0.f};
        const _Float16* Pr = (const _Float16*)&Ssc[fm & 7][0] + (fq << 3);
        #pragma unroll
        for (int kb = 0; kb < 4; ++kb) {
            f16x8 vf = *(const f16x8*)(vfb + (kb << 5));
            f16x8 a = *(const f16x8*)(Pr + ((((wave << 2) + kb)) << 5));
            acc = __builtin_amdgcn_mfma_f32_16x16x32_f16(a, vf, acc, 0, 0, 0);
        }
        if (lane < 32) {   // C rows 0-7 live in quads 0-1
            #pragma unroll
            for (int i = 0; i < 4; ++i)
                part[(wave << 7) + (((fq << 2) + i) << 4) + fm] = acc[i];
        }
        __syncthreads();   // B4: partials visible (also: P reads done)

        // ---- reduce 8 partials + store; rotate active waves by chunk ----
        const int rw = (wave - chunk) & 7;
        if (rw < 2) {
            const int t2 = (rw << 6) + lane;
            const int r = t2 >> 4, d = t2 & 15;
            float o = 0.f;
            #pragma unroll
            for (int w = 0; w < 8; ++w) o += part[(w << 7) + t2];
            const float inv = 1.0f / sums[sb][r];
            const int q = qbase + r;
            const int h = head >> 3, bp = head & 7;
            float* dst = Ob + (((size_t)(h >> 1)) << 18)
                            + ((size_t)(((h & 1) << 9) + (q >> 1)) << 8)
                            + ((q & 1) << 7) + (bp << 4) + d;
            *dst = o * inv;
        }
    }
}

// ---------------------------------------------------------------------------
extern "C" void kernel_launch(void* const* d_in, const int* in_sizes, int n_in,
                              void* d_out, int out_size, void* d_ws, size_t ws_size,
                              hipStream_t stream) {
    const float* x  = (const float*)d_in[0];
    const float* y  = (const float*)d_in[1];
    const float* Wq = (const float*)d_in[2];
    const float* bq = (const float*)d_in[3];
    const float* Wk = (const float*)d_in[4];
    const float* bk = (const float*)d_in[5];
    const float* Wv = (const float*)d_in[6];
    const float* bv = (const float*)d_in[7];
    const float* Wo = (const float*)d_in[8];
    const float* bo = (const float*)d_in[9];
    float* out = (float*)d_out;

    float*     Q  = (float*)d_ws;                       // 2M floats
    float*     K  = Q + 2097152;                        // 2M floats
    _Float16*  VT = (_Float16*)(K + 2097152);           // 2M f16 (1M floats)
    float*     AO = (float*)d_ws + 5242880;             // 2M floats
    _Float16*  WP = (_Float16*)((float*)d_ws + 7340032);// 512K f16 (256K floats)

    prepW<<<dim3(16, 4), dim3(256), 0, stream>>>(Wq, Wk, Wv, Wo, WP);
    gemmQKV<<<dim3(64, 4, 3), dim3(512), 0, stream>>>(x, y, WP, bq, bk, bv,
                                                      Q, K, (float*)VT);
    attn<<<dim3(128, 6), dim3(512), 0, stream>>>(Q, K, VT, AO);
    gemmOut<<<dim3(64, 4), dim3(512), 0, stream>>>(AO, WP, bo, out);
}